// Round 5
// baseline (960.875 us; speedup 1.0000x reference)
//
#include <hip/hip_runtime.h>

// LGA3: 3 chained local-guided-aggregation passes, rolling-accumulator stencil.
// Both cost planes AND weights staged to LDS via double-buffered global_load_lds.
// cost [B=2, D=64, H=384, W=768] fp32, weights [B, 75, H, W] fp32.
// out[b,d,h,w] = sum_{i,j in 5x5} w0*c[d-1,h+i-2,w+j-2] + w1*c[d,..] + w2*c[d+1,..]
//
// Block: 64-wide w chunk x all 64 d x HSEG=16 output rows; 512 thr (8 waves).
// Per input row r: cost tile 66 planes x 72 floats (rows 0/65 = d-pad zeros),
// weight tile 75 channels x 64 floats = the exact (outrow, tap) pairs iter r
// consumes (each pair consumed exactly once per block). Stage of iter r+1
// overlaps compute of iter r; one __syncthreads per iter swaps buffers.

#define B_ 2
#define D_ 64
#define H_ 384
#define W_ 768
static constexpr int HW    = H_ * W_;
static constexpr int DPT   = 8;          // disparities per thread
static constexpr int NTY   = D_ / DPT;   // 8 waves
static constexpr int WT    = 64;
static constexpr int HSEG  = 16;         // output rows per block
static constexpr int RITER = HSEG + 4;   // 20 streamed input rows
static constexpr int LROW  = 72;         // floats per cost plane row
static constexpr int LPL   = 66;         // 0 = zero(d=-1), 1..64 = d, 65 = zero(d=64)
static constexpr int NCH_C = 18;         // 1 KiB chunks per cost-row stage
static constexpr int NCH_W = 19;         // 1 KiB chunks per weight stage (76 padded ch)
static constexpr int WCH   = 76;         // padded weight channels in LDS

__device__ __forceinline__ void gld_lds16(const float* g, float* l) {
  __builtin_amdgcn_global_load_lds((const __attribute__((address_space(1))) unsigned int*)g,
                                   (__attribute__((address_space(3))) unsigned int*)l,
                                   16, 0, 0);
}

__global__ __launch_bounds__(512, 4) void lga_pass(const float* __restrict__ src,
                                                   const float* __restrict__ wts,
                                                   float* __restrict__ dst) {
  __shared__ float cl[2][LPL * LROW];     // 38016 B
  __shared__ float wl[2][WCH * 64];       // 38912 B

  const int tx = threadIdx.x;             // 0..63 (lane; wave = ty)
  const int ty = threadIdx.y;             // 0..7
  const int bx = blockIdx.x;
  const int w0 = bx * WT, w = w0 + tx;
  const int hs = blockIdx.y * HSEG;
  const int b  = blockIdx.z;
  const int d0 = ty * DPT;

  const float* sb = src + (size_t)b * D_ * HW;
  const float* wb = wts + (size_t)b * 75 * HW;

  // one-time zero of the d-pad planes (rows 0 and 65 of both cost buffers)
  {
    const int flat = ty * WT + tx;
    if (flat < 2 * 2 * LROW) {
      const int q   = flat / (2 * LROW);
      const int rem = flat - q * (2 * LROW);
      const int row = (rem >= LROW) ? (LPL - 1) : 0;
      const int col = (rem >= LROW) ? rem - LROW : rem;
      cl[q][row * LROW + col] = 0.f;
    }
  }

  // async stage of one cost row (64 planes x 288 B) into buffer `buf`
  auto stage_c = [&](int buf, int h_in) {
#pragma unroll
    for (int q = 0; q < 3; ++q) {
      const int c = ty + q * 8;                      // chunk id, wave-uniform
      if (c < NCH_C) {
        const int G = c * 64 + tx;                   // granule 0..1151
        const int d = G / NCH_C;
        const int k = G - d * NCH_C;
        long idx = (long)d * HW + (long)h_in * W_ + (w0 - 4) + (k << 2);
        idx = idx < 0 ? 0 : idx;
        const long mx = (long)D_ * HW - 4;
        idx = idx > mx ? mx : idx;
        gld_lds16(sb + idx, &cl[buf][LROW + c * 256]);
      }
    }
  };

  // async stage of the 75 weight channels iter `rr` consumes:
  // channel ch = s*15 + g*5 + j  ->  weights[b][(4-s)*5+j+25g][hs+rr-4+s][w0..w0+63]
  auto stage_w = [&](int buf, int rr) {
#pragma unroll
    for (int q = 0; q < 3; ++q) {
      const int ci = ty + q * 8;                     // chunk id, wave-uniform
      if (ci < NCH_W) {
        int ch = ci * 4 + (tx >> 4);
        ch = ch > 74 ? 74 : ch;                      // pad chunk 18 (dup, never read)
        const int s  = ch / 15;
        const int t  = ch - s * 15;
        const int g  = t / 5;
        const int j  = t - g * 5;
        const int cw = (4 - s) * 5 + j + g * 25;
        int o = hs + rr - 4 + s;
        o = o < 0 ? 0 : (o >= H_ ? H_ - 1 : o);      // clamped rows never consumed
        const float* p = wb + (size_t)cw * HW + (size_t)o * W_ + w0 + ((tx & 15) << 2);
        gld_lds16(p, &wl[buf][ci * 256]);
      }
    }
  };

  // prologue: stage iter 0 into buffer 0
  {
    const int h0 = hs - 2;
    if (h0 >= 0) stage_c(0, h0);
    stage_w(0, 0);
  }
  __syncthreads();

  float acc[5][DPT];
#pragma unroll
  for (int s = 0; s < 5; ++s)
#pragma unroll
    for (int k = 0; k < DPT; ++k) acc[s][k] = 0.f;

  int n = 0;
#pragma unroll 1
  for (int r = 0; r < RITER; ++r) {
    // prefetch iter r+1 into the other buffer (overlaps compute below)
    if (r + 1 < RITER) {
      const int h_nx = hs - 2 + r + 1;
      if ((unsigned)h_nx < (unsigned)H_) stage_c(n ^ 1, h_nx);
      stage_w(n ^ 1, r + 1);
    }

    const int h_in = hs - 2 + r;
    if ((unsigned)h_in < (unsigned)H_) {             // wave-uniform
      float* cur        = cl[n];
      const float* wcur = wl[n];

      // w-edge zero padding: each wave zeroes halo cols of the planes it reads
      if (bx == 0 && tx < 20)
        cur[(d0 + (tx >> 1)) * LROW + 2 + (tx & 1)] = 0.f;
      if (bx == (W_ / WT - 1) && tx < 20)
        cur[(d0 + (tx >> 1)) * LROW + 68 + (tx & 1)] = 0.f;

      // vv[j][m] = cost[d0-1+m, h_in, w+j-2]
      float vv[5][DPT + 2];
#pragma unroll
      for (int j = 0; j < 5; ++j)
#pragma unroll
        for (int m = 0; m < DPT + 2; ++m)
          vv[j][m] = cur[(d0 + m) * LROW + tx + j + 2];

      // slot s -> output row hs+r-4+s, tap row 4-s; weights from LDS (imm offsets)
#pragma unroll
      for (int s = 0; s < 5; ++s) {
        if ((unsigned)(r - 4 + s) < (unsigned)HSEG) {
          const float* wsl = wcur + s * 15 * 64 + tx;
#pragma unroll
          for (int j = 0; j < 5; ++j) {
            const float w0v = wsl[(size_t)(j)      * 64];
            const float w1v = wsl[(size_t)(5 + j)  * 64];
            const float w2v = wsl[(size_t)(10 + j) * 64];
#pragma unroll
            for (int k = 0; k < DPT; ++k)
              acc[s][k] = fmaf(w0v, vv[j][k],
                          fmaf(w1v, vv[j][k + 1],
                          fmaf(w2v, vv[j][k + 2], acc[s][k])));
          }
        }
      }
    }

    // slot 0 complete -> write output row hs+r-4
    if (r >= 4) {
      const int o = hs + r - 4;
      float* dp = dst + (((size_t)b * D_ + d0) * H_ + o) * W_ + w;
#pragma unroll
      for (int k = 0; k < DPT; ++k) dp[(size_t)k * HW] = acc[0][k];
    }

    // rotate slots (static indices)
#pragma unroll
    for (int s = 0; s < 4; ++s)
#pragma unroll
      for (int k = 0; k < DPT; ++k) acc[s][k] = acc[s + 1][k];
#pragma unroll
    for (int k = 0; k < DPT; ++k) acc[4][k] = 0.f;

    __syncthreads();   // drains global_load_lds; swap buffers
    n ^= 1;
  }
}

extern "C" void kernel_launch(void* const* d_in, const int* in_sizes, int n_in,
                              void* d_out, int out_size, void* d_ws, size_t ws_size,
                              hipStream_t stream) {
  const float* cost = (const float*)d_in[0];
  const float* wts  = (const float*)d_in[1];
  float* out = (float*)d_out;
  float* ws  = (float*)d_ws;

  dim3 grid(W_ / WT, H_ / HSEG, B_);   // 12 x 24 x 2 = 576 blocks
  dim3 block(WT, NTY);                 // 64 x 8 = 512 threads

  lga_pass<<<grid, block, 0, stream>>>(cost, wts, out);
  lga_pass<<<grid, block, 0, stream>>>(out, wts, ws);
  lga_pass<<<grid, block, 0, stream>>>(ws, wts, out);
}